// Round 11
// baseline (247.846 us; speedup 1.0000x reference)
//
#include <hip/hip_runtime.h>
#include <hip/hip_bf16.h>

// Problem dims (fixed by reference)
//   B=128, T=256, D_MODEL=128, D_INNER=256, D_STATE=16, D_CONV=4, DT_RANK=8
// I/O dtype: float32. MFMA bf16 for in_proj/x_proj/fused-tail. R22:
//  - R10 post-mortem: scan12 == scan10 (57.6 vs 57.4us) -> packing neutral;
//    scan FROZEN (floor = dependent chain at 2-3 blocks/CU).
//  - od_k2: the tail's worst-occupancy kernel was od_k (1024 waves total =
//    1 wave/SIMD -- zero latency hiding for its 72 fragmented A/G loads).
//    Split the 3 conv-shifts across 3 waves: block 192thr per 16-row m-tile,
//    grid 1024; wave k computes the K=256 partial for shift k (64 MFMA);
//    waves 1,2 -> LDS P[2][64][33] (pad: conflict-free); wave 0 sums + LN.
//    3x waves/SIMD, same total MFMA, numerics identical.
//  - Everything else frozen at R8/R10 best (247.0/247.7us).
// Outputs: h (128,128,128) then x_skip (128,256,128), fp32, concatenated.

typedef __attribute__((ext_vector_type(8))) short bf16x8;
typedef __attribute__((ext_vector_type(4))) short bf16x4;
typedef __attribute__((ext_vector_type(4))) float f32x4;
using bf16 = __hip_bfloat16;

static __device__ __forceinline__ short f2s(float v) {
  union { bf16 b; short s; } u; u.b = (bf16)v; return u.s;
}
static __device__ __forceinline__ float s2f(short s) {
  union { short s; bf16 b; } u; u.s = s; return (float)u.b;
}

// packed stream index: (b, d, t) -> [b][g=d>>5][c=t>>3][dl=d&31][tt=t&7]
static __device__ __forceinline__ size_t pidx(int b, int d, int t) {
  return ((((size_t)b * 8 + (d >> 5)) * 32 + (t >> 3)) * 32 + (d & 31)) * 8 + (t & 7);
}

// ---------------------------------------------------------------------------
// prep_all: three independent prep jobs in one launch.
//  blocks [0,4096):    cvt_x -- x fp32 -> bf16 xb AND x_skip copy (out1)
//  blocks [4096,4416): prep_w -- ipw->bf16 ipwb; x_proj_w->wxb (rows 40+ = 0)
//  blocks [4416,4800): g_prep -- G_k[co,e] = sum_dm dwn[co,dm,k]*opw[dm,e]
// ---------------------------------------------------------------------------
__global__ __launch_bounds__(256) void prep_all(const float* __restrict__ x,
                                                const float* __restrict__ ipw,
                                                const float* __restrict__ xpw,
                                                const float* __restrict__ dwn,
                                                const float* __restrict__ opw,
                                                short* __restrict__ xb,
                                                float* __restrict__ out1,
                                                short* __restrict__ ipwb,
                                                short* __restrict__ wxb,
                                                short* __restrict__ G) {
  const int bid = blockIdx.x;
  if (bid < 4096) {
    int i = (bid * 256 + threadIdx.x) * 4;
    f32x4 v = *(const f32x4*)(x + i);
    bf16x4 o;
    o[0] = f2s(v[0]); o[1] = f2s(v[1]); o[2] = f2s(v[2]); o[3] = f2s(v[3]);
    *(bf16x4*)(xb + i) = o;
    *(f32x4*)(out1 + i) = v;
  } else if (bid < 4416) {
    int idx = (bid - 4096) * 256 + threadIdx.x;   // 0 .. 81919
    if (idx < 65536) {
      ipwb[idx] = f2s(ipw[idx]);
    } else {
      int j = idx - 65536;          // n*256 + k
      int n = j >> 8;
      wxb[j] = (n < 40) ? f2s(xpw[j]) : (short)0;
    }
  } else {
    const int jb = bid - 4416;      // 0 .. 383
    const int k  = jb >> 7;
    const int co = jb & 127;
    const int e  = threadIdx.x;
    float acc = 0.f;
    for (int dm = 0; dm < 128; ++dm) {
      acc += dwn[(co * 128 + dm) * 3 + k] * opw[dm * 256 + e];
    }
    G[(size_t)(k * 128 + co) * 256 + e] = f2s(acc);
  }
}

// ---------------------------------------------------------------------------
// inproj_k: in_proj MFMA (M=32768 bt, N=512, K=128) with TRANSPOSED output.
// Block 256thr/4 waves, tile 64m x 64n. Epilogue: C-frags (+silu for z half)
// -> LDS LT[d_local][t_local] -> b128 stores. xc half -> xcpreT (b,d,t);
// z half -> zP PACKED [b][g][c][dl][tt] for scan12's coalesced reads.
// ---------------------------------------------------------------------------
__global__ __launch_bounds__(256) void inproj_k(const short* __restrict__ A,
                                                const short* __restrict__ W,
                                                short* __restrict__ xcpreT,
                                                short* __restrict__ zP) {
  const int m_base = blockIdx.x * 64;
  const int n_base = blockIdx.y * 64;
  const int wave = threadIdx.x >> 6;
  const int lane = threadIdx.x & 63;
  const int r16  = lane & 15;
  const int quad = lane >> 4;
  f32x4 acc[4] = {};
  const short* Ap = A + (size_t)(m_base + wave * 16 + r16) * 128 + quad * 8;
  const short* Wp = W + (size_t)(n_base + r16) * 128 + quad * 8;
#pragma unroll
  for (int k0 = 0; k0 < 128; k0 += 32) {
    bf16x8 a = *(const bf16x8*)(Ap + k0);
#pragma unroll
    for (int j = 0; j < 4; ++j) {
      bf16x8 b = *(const bf16x8*)(Wp + (size_t)j * 16 * 128 + k0);
      acc[j] = __builtin_amdgcn_mfma_f32_16x16x32_bf16(a, b, acc[j], 0, 0, 0);
    }
  }
  __shared__ short LT[64][72];                 // [d_local][t_local], pad 8
  const bool isz = (n_base >= 256);
#pragma unroll
  for (int j = 0; j < 4; ++j) {
#pragma unroll
    for (int r = 0; r < 4; ++r) {
      float v = acc[j][r];
      short s = isz ? f2s(v / (1.f + __expf(-v))) : f2s(v);
      LT[j * 16 + r16][wave * 16 + quad * 4 + r] = s;
    }
  }
  __syncthreads();
  const int bb = m_base >> 8;
  const int tbase = m_base & 255;
  const int dbase = isz ? (n_base - 256) : n_base;
#pragma unroll
  for (int it = 0; it < 2; ++it) {
    const int dw = (threadIdx.x >> 3) + it * 32;
    const int tc = (threadIdx.x & 7) * 8;      // t offset within 64-t tile
    bf16x8 v = *(const bf16x8*)(&LT[dw][tc]);
    const int d = dbase + dw;
    const int t = tbase + tc;
    if (isz) {
      *(bf16x8*)(zP + pidx(bb, d, t)) = v;
    } else {
      *(bf16x8*)(xcpreT + ((size_t)(bb * 256 + d)) * 256 + t) = v;
    }
  }
}

// ---------------------------------------------------------------------------
// mid_k v3: fused depthwise conv+silu + x_proj MFMA + delta(softplus).
// Block = (b, 32-t eighth); 1024 blocks x 256 thr; LDS 17.9KB -> 4 blocks/CU.
//  phase 1: conv from xcpreT (b,d,t) via 2 bf16x8 vector loads; out -> xcP
//           PACKED (regs, 16B/thread) + XC[t][d] LDS scalar.
//  phase 2: x_proj MFMA M=32 N=48(used 40) K=256; dt->DTL; B/C->SBC fp32.
//  phase 3: delta = softplus(dt . dtw[d] + dtb[d]) -> dP PACKED.
// ---------------------------------------------------------------------------
__global__ __launch_bounds__(256, 4) void mid_k(const short* __restrict__ xcpreT,
                                                const float* __restrict__ cw,
                                                const float* __restrict__ cb,
                                                const short* __restrict__ wxb,
                                                const float* __restrict__ dtw,
                                                const float* __restrict__ dtb,
                                                short* __restrict__ xcP,
                                                short* __restrict__ dP,
                                                float* __restrict__ SBC) {
  const int b  = blockIdx.x >> 3;
  const int t0 = (blockIdx.x & 7) * 32;       // t-eighth base
  const int tg = threadIdx.x >> 6;            // 4 groups of 8 t
  const int dl = threadIdx.x & 63;
  const int tA = t0 + tg * 8;
  __shared__ short XC[32][264];               // [t-local][d] bf16, pad 8
  __shared__ float DTL[32][8];                // dt cols per t-local
  // ---- phase 1: conv+silu, 4 d-tiles x 8 t per thread, vector loads ----
#pragma unroll
  for (int dtile = 0; dtile < 4; ++dtile) {
    const int d = dtile * 64 + dl;
    const float w0 = cw[d * 4], w1 = cw[d * 4 + 1];
    const float w2 = cw[d * 4 + 2], w3 = cw[d * 4 + 3];
    const float bias = cb[d];
    const size_t base = ((size_t)b * 256 + d) * 256;   // t-row base
    bf16x8 v = *(const bf16x8*)(xcpreT + base + tA);
    bf16x8 hp = {};
    if (tA >= 8) hp = *(const bf16x8*)(xcpreT + base + tA - 8);
    float x3 = s2f(hp[5]), x2 = s2f(hp[6]), x1 = s2f(hp[7]);
    bf16x8 outv;
#pragma unroll
    for (int i = 0; i < 8; ++i) {
      const float cur = s2f(v[i]);
      const float a = bias + x3 * w0 + x2 * w1 + x1 * w2 + cur * w3;
      const short s = f2s(a / (1.f + __expf(-a)));
      outv[i] = s;
      XC[tg * 8 + i][d] = s;
      x3 = x2; x2 = x1; x1 = cur;
    }
    *(bf16x8*)(xcP + pidx(b, d, tA)) = outv;
  }
  __syncthreads();
  // ---- phase 2: x_proj MFMA (A = XC, W = wxb), waves 0..2 ----
  if (tg < 3) {
    const int r16  = dl & 15;
    const int quad = dl >> 4;
    f32x4 acc0 = {}, acc1 = {};
    const short* Wp = wxb + (size_t)(tg * 16 + r16) * 256 + quad * 8;
#pragma unroll
    for (int k0 = 0; k0 < 256; k0 += 32) {
      bf16x8 bb = *(const bf16x8*)(Wp + k0);
      bf16x8 a0 = *(const bf16x8*)(&XC[r16][quad * 8 + k0]);
      bf16x8 a1 = *(const bf16x8*)(&XC[16 + r16][quad * 8 + k0]);
      acc0 = __builtin_amdgcn_mfma_f32_16x16x32_bf16(a0, bb, acc0, 0, 0, 0);
      acc1 = __builtin_amdgcn_mfma_f32_16x16x32_bf16(a1, bb, acc1, 0, 0, 0);
    }
    const int col = tg * 16 + r16;
#pragma unroll
    for (int r = 0; r < 4; ++r) {
      const int tl0 = quad * 4 + r;
      const int tl1 = 16 + quad * 4 + r;
      if (col < 8) {
        DTL[tl0][col] = acc0[r];
        DTL[tl1][col] = acc1[r];
      } else if (col < 40) {
        SBC[((size_t)b * 256 + t0 + tl0) * 32 + (col - 8)] = acc0[r];
        SBC[((size_t)b * 256 + t0 + tl1) * 32 + (col - 8)] = acc1[r];
      }
    }
  }
  __syncthreads();
  // ---- phase 3: delta = softplus(dt . dtw + dtb) -> dP packed ----
#pragma unroll
  for (int dtile = 0; dtile < 4; ++dtile) {
    const int d = dtile * 64 + dl;
    float wd[8];
#pragma unroll
    for (int j = 0; j < 8; ++j) wd[j] = dtw[d * 8 + j];
    const float bd = dtb[d];
    bf16x8 dv;
#pragma unroll
    for (int i = 0; i < 8; ++i) {
      const int tl = tg * 8 + i;
      const f32x4 p0 = *(const f32x4*)(&DTL[tl][0]);
      const f32x4 p1 = *(const f32x4*)(&DTL[tl][4]);
      float acc = bd;
#pragma unroll
      for (int j = 0; j < 4; ++j) acc += p0[j] * wd[j] + p1[j] * wd[4 + j];
      const float delta = (acc > 20.f) ? acc : __logf(1.f + __expf(acc));
      dv[i] = f2s(delta);
    }
    *(bf16x8*)(dP + pidx(b, d, tA)) = dv;
  }
}

// ---------------------------------------------------------------------------
// scan12 (FROZEN): R8 skeleton + packed u/d/z reads. Block = (b, group of 32
// d), 128 thr = 32 d x 4 lanes; lane owns 4 of 16 states, serial T=256.
// u/d/z packed streams: one contiguous 256B segment per wave-load. uu/dd/zz
// [4] named rotation, 4-phase unrolled; chunk c+4 issued right after chunk c
// consumed. S (B/C fp32) 2-phase LDS, 32KB. y scatter store (q==0).
// ---------------------------------------------------------------------------
#define LDS_S(SB, CH) do {                                                   \
    _Pragma("unroll")                                                        \
    for (int j_ = 0; j_ < 8; ++j_) {                                         \
      SBr[SB][j_] = *(const f32x4*)(&S[(CH) * 8 + j_][q * 4]);               \
      SCr[SB][j_] = *(const f32x4*)(&S[(CH) * 8 + j_][16 + q * 4]);          \
    }                                                                        \
  } while (0)

#define LDG(GB, CH) do {                                                     \
    if ((CH) < 32) {                                                         \
      uu[GB] = *(const bf16x8*)(xcP + pb + (size_t)(CH) * 256);              \
      dd[GB] = *(const bf16x8*)(dP + pb + (size_t)(CH) * 256);               \
      if (q == 0) zz[GB] = *(const bf16x8*)(zP + pb + (size_t)(CH) * 256);   \
    }                                                                        \
  } while (0)

#define CHUNK(GB, SB, CH) do {                                               \
    _Pragma("unroll")                                                        \
    for (int tt_ = 0; tt_ < 8; ++tt_) {                                      \
      const int t_ = (CH) * 8 + tt_;                                         \
      const float delta_ = s2f(dd[GB][tt_]);                                 \
      const float u_ = s2f(uu[GB][tt_]);                                     \
      const float du_ = delta_ * u_;                                         \
      const f32x4 Bq_ = SBr[SB][tt_];                                        \
      const f32x4 Cq_ = SCr[SB][tt_];                                        \
      float yt_ = 0.f;                                                       \
      _Pragma("unroll")                                                      \
      for (int n_ = 0; n_ < 4; ++n_) {                                       \
        const float dA_ = __builtin_amdgcn_exp2f(delta_ * A2[n_]);           \
        h[n_] = dA_ * h[n_] + du_ * Bq_[n_];                                 \
        yt_ += h[n_] * Cq_[n_];                                              \
      }                                                                      \
      yt_ += __shfl_xor(yt_, 1);                                             \
      yt_ += __shfl_xor(yt_, 2);                                             \
      if (q == 0)                                                            \
        yb[(rb + t_) * 256 + d] = f2s((yt_ + u_ * Dv) * s2f(zz[GB][tt_]));   \
    }                                                                        \
  } while (0)

__global__ __launch_bounds__(128, 2) void scan12(const float* __restrict__ SBC,
                                                 const short* __restrict__ xcP,
                                                 const short* __restrict__ dP,
                                                 const short* __restrict__ zP,
                                                 const float* __restrict__ alog,
                                                 const float* __restrict__ Dp,
                                                 short* __restrict__ yb) {
  const int g = blockIdx.x & 7;
  const int b = blockIdx.x >> 3;
  const int q = threadIdx.x & 3;
  const int dl = threadIdx.x >> 2;            // 0..31 within group
  const int d = g * 32 + dl;
  const size_t rb = (size_t)b * 256;
  __shared__ float S[256][32];                // B(16)|C(16) fp32 per t, 32 KB
  for (int i = threadIdx.x; i < 2048; i += 128) {
    *(f32x4*)(&S[i >> 3][(i & 7) * 4]) =
        *(const f32x4*)(SBC + (size_t)b * 8192 + i * 4);
  }
  float A2[4];
#pragma unroll
  for (int n = 0; n < 4; ++n)
    A2[n] = -__expf(alog[d * 16 + q * 4 + n]) * 1.44269504089f;
  const float Dv = Dp[d];
  float h[4] = {0.f, 0.f, 0.f, 0.f};
  // packed per-lane base: [b][g][c=0][dl][0]
  const size_t pb = (((size_t)b * 8 + g) * 32) * 256 + (size_t)dl * 8;
  f32x4 SBr[2][8], SCr[2][8];
  bf16x8 uu[4], dd[4];
  bf16x8 zz[4] = {};
  // 4-deep global prologue (issues before the LDS-fill barrier)
  LDG(0, 0); LDG(1, 1); LDG(2, 2); LDG(3, 3);
  __syncthreads();
  LDS_S(0, 0);
  for (int c = 0; c < 32; c += 4) {
    LDS_S(1, c + 1);
    CHUNK(0, 0, c);
    LDG(0, c + 4);
    LDS_S(0, c + 2);
    CHUNK(1, 1, c + 1);
    LDG(1, c + 5);
    LDS_S(1, c + 3);
    CHUNK(2, 0, c + 2);
    LDG(2, c + 6);
    if (c + 4 < 32) LDS_S(0, c + 4);
    CHUNK(3, 1, c + 3);
    LDG(3, c + 7);
  }
}

// ---------------------------------------------------------------------------
// od_k2: fused out_proj + strided down-conv + bias + LayerNorm, K-SPLIT.
//   pre[b,to,co] = sum_{k=0..2} yb[b, 2to+k-1, :] . G_k[co, :]  + db[co]
//   out = LN(pre) over co (128), eps 1e-5.
// Grid 1024 blocks (16-row m-tiles) x 192 thr (3 waves). Wave k computes the
// K=256 partial for conv-shift k (64 MFMA); waves 1,2 park C-frags in LDS
// P[2][64][33] (pad 33 -> (lane+idx)%32 bank, conflict-free); wave 0 sums the
// three partials and runs bias + LN (16-lane shfl reductions) + store.
// 3072 waves total = 3 waves/SIMD (was 1) -- 3x latency hiding.
// ---------------------------------------------------------------------------
__global__ __launch_bounds__(192) void od_k(const short* __restrict__ yb,
                                            const short* __restrict__ G,
                                            const float* __restrict__ db,
                                            const float* __restrict__ lng,
                                            const float* __restrict__ lnb,
                                            float* __restrict__ out) {
  const int wave = threadIdx.x >> 6;           // = conv shift k
  const int lane = threadIdx.x & 63;
  const int r16  = lane & 15;
  const int quad = lane >> 4;
  const int m_base = blockIdx.x * 16;
  const int ma = m_base + r16;
  const int ba = ma >> 7, toa = ma & 127;
  const int k = wave;
  f32x4 acc[8] = {};
  const bf16x8 az = {};
  const int tp = 2 * toa + k - 1;
  const bool valid = (tp >= 0) && (tp < 256);
  const int tpc = tp < 0 ? 0 : (tp > 255 ? 255 : tp);
  const short* Ap = yb + (size_t)(ba * 256 + tpc) * 256 + quad * 8;
  const short* Gp = G + (size_t)(k * 128 + r16) * 256 + quad * 8;
#pragma unroll
  for (int k0 = 0; k0 < 256; k0 += 32) {
    bf16x8 a = *(const bf16x8*)(Ap + k0);
    a = valid ? a : az;
#pragma unroll
    for (int j = 0; j < 8; ++j) {
      bf16x8 g = *(const bf16x8*)(Gp + (size_t)j * 16 * 256 + k0);
      acc[j] = __builtin_amdgcn_mfma_f32_16x16x32_bf16(a, g, acc[j], 0, 0, 0);
    }
  }
  __shared__ float P[2][64][33];               // partials from waves 1,2
  if (wave > 0) {
#pragma unroll
    for (int j = 0; j < 8; ++j)
#pragma unroll
      for (int r = 0; r < 4; ++r)
        P[wave - 1][lane][j * 4 + r] = acc[j][r];
  }
  __syncthreads();
  if (wave == 0) {
    float dbv[8], g8[8], be8[8];
#pragma unroll
    for (int j = 0; j < 8; ++j) {
      const int col = j * 16 + r16;
      dbv[j] = db[col]; g8[j] = lng[col]; be8[j] = lnb[col];
    }
#pragma unroll
    for (int r = 0; r < 4; ++r) {
      float v[8];
      float s = 0.f;
#pragma unroll
      for (int j = 0; j < 8; ++j) {
        v[j] = acc[j][r] + P[0][lane][j * 4 + r] + P[1][lane][j * 4 + r]
             + dbv[j];
        s += v[j];
      }
      s += __shfl_xor(s, 1); s += __shfl_xor(s, 2);
      s += __shfl_xor(s, 4); s += __shfl_xor(s, 8);
      const float mu = s * (1.0f / 128.0f);
      float vs = 0.f;
#pragma unroll
      for (int j = 0; j < 8; ++j) { const float dd = v[j] - mu; vs += dd * dd; }
      vs += __shfl_xor(vs, 1); vs += __shfl_xor(vs, 2);
      vs += __shfl_xor(vs, 4); vs += __shfl_xor(vs, 8);
      const float rstd = rsqrtf(vs * (1.0f / 128.0f) + 1e-5f);
      const int rowm = m_base + quad * 4 + r;
#pragma unroll
      for (int j = 0; j < 8; ++j) {
        out[(size_t)rowm * 128 + j * 16 + r16] =
            (v[j] - mu) * rstd * g8[j] + be8[j];
      }
    }
  }
}

// ---------------------------------------------------------------------------
// Workspace layout (bytes), peak 92,471,296 == proven-safe bound:
//   [0,16M)      xcpreT bf16 (inproj->mid_k) -> yb bf16 (scan->od_k)
//   [16M,32M)    xcP bf16 packed (mid_k->scan)
//   [32M,48M)    zP bf16 packed (inproj->scan)
//   [48M,64M)    dP bf16 packed (mid_k->scan)
//   [64M,68.2M)  SBC fp32 4MB (mid_k->scan)
//   [68.2M..71.5M) G bf16 196,608B (prep_all->od_k)
//   [72M,80.4M)  xb bf16 8.4MB (prep_all->inproj)
//   [88M,88.1M)  ipwb bf16 131,072B (prep_all->inproj)
// d_out staging: wxb (32KB bf16) at out0 base (od_k writes out0 LAST);
// out1 written once by prep_all.
// ---------------------------------------------------------------------------
static const size_t O_XCPRE = 0;            // also yb
static const size_t O_XCP   = 16777216;
static const size_t O_ZP    = 33554432;
static const size_t O_DP    = 50331648;
static const size_t O_SBC   = 67108864;     // 4,194,304 B
static const size_t O_G     = 71303168;     // 196,608 B
static const size_t O_XB    = 75497472;
static const size_t O_IPWB  = 92274688;     // 131,072 B -> end 92,405,760

extern "C" void kernel_launch(void* const* d_in, const int* in_sizes, int n_in,
                              void* d_out, int out_size, void* d_ws, size_t ws_size,
                              hipStream_t stream) {
  const float* x    = (const float*)d_in[0];
  const float* ipw  = (const float*)d_in[1];
  const float* cw   = (const float*)d_in[2];
  const float* cb   = (const float*)d_in[3];
  const float* xpw  = (const float*)d_in[4];
  const float* dtw  = (const float*)d_in[5];
  const float* dtb  = (const float*)d_in[6];
  const float* alog = (const float*)d_in[7];
  const float* Dp   = (const float*)d_in[8];
  const float* opw  = (const float*)d_in[9];
  const float* dw   = (const float*)d_in[10];
  const float* db   = (const float*)d_in[11];
  const float* lng  = (const float*)d_in[12];
  const float* lnb  = (const float*)d_in[13];

  char*  ws     = (char*)d_ws;
  short* xcpreT = (short*)(ws + O_XCPRE);
  short* yb     = (short*)(ws + O_XCPRE);  // alias (xcpreT dead after mid_k)
  short* xcP    = (short*)(ws + O_XCP);
  short* zP     = (short*)(ws + O_ZP);
  short* dP     = (short*)(ws + O_DP);
  float* SBC    = (float*)(ws + O_SBC);
  short* G      = (short*)(ws + O_G);
  short* xb     = (short*)(ws + O_XB);
  short* ipwb   = (short*)(ws + O_IPWB);
  float* out    = (float*)d_out;
  short* wxb    = (short*)out;             // out0 staging; od_k writes last
  float* out1   = out + 2097152;

  // 0. all prep: x->bf16 + x_skip copy; ipw/xpw->bf16; G = dwn @ opw
  prep_all<<<4800, 256, 0, stream>>>(x, ipw, xpw, dw, opw,
                                     xb, out1, ipwb, wxb, G);
  // 1. in_proj MFMA -> xcpreT (b,d,t) + zP packed via LDS tile
  inproj_k<<<dim3(512, 8), 256, 0, stream>>>(xb, ipwb, xcpreT, zP);
  // 2. fused conv+silu + x_proj + delta -> xcP/dP packed + SBC
  mid_k<<<1024, 256, 0, stream>>>(xcpreT, cw, cb, wxb, dtw, dtb,
                                  xcP, dP, SBC);
  // 3. state-parallel scan (FROZEN) -> yb
  scan12<<<1024, 128, 0, stream>>>(SBC, xcP, dP, zP, alog, Dp, yb);
  // 4. fused out_proj + down-conv + bias + LayerNorm (3-wave K-split) -> out0
  od_k<<<1024, 192, 0, stream>>>(yb, G, db, lng, lnb, out);
}

// Round 12
// 224.976 us; speedup vs baseline: 1.1017x; 1.1017x over previous
//
#include <hip/hip_runtime.h>
#include <hip/hip_bf16.h>

// Problem dims (fixed by reference)
//   B=128, T=256, D_MODEL=128, D_INNER=256, D_STATE=16, D_CONV=4, DT_RANK=8
// I/O dtype: float32. MFMA bf16 for in_proj/x_proj/fused-tail. R23:
//  - R11 post-mortem: od_k2 3-wave split NEUTRAL (247.8 vs 247.7) and
//    regressed absmax (partial-sum reorder) -> REVERTED to R8 od_k.
//    Ledger: scan 57.6 + prep ~10 + od ~10 + gaps ~15 => inproj+mid own
//    ~100-150us. They are separated by a full drain + a 33.6MB xcpreT
//    round-trip that exists only to hand conv its input.
//  - front_k: in_proj + conv/silu + x_proj + delta fused per (b, 64-t
//    quarter). A-tile (80 rows, zero-filled t<0) LDS-staged once; xc-GEMM
//    writes C-frags straight into XC[t][d] (xcpreT round-trip deleted);
//    z-GEMM reuses A-tile -> LT transpose -> packed zP; conv from XC (regs,
//    write-back after barrier); x_proj + delta as mid_k. 75KB LDS -> 2
//    blocks/CU, grid 512 fully co-resident. Pipeline 5 -> 4 kernels.
//  - scan12 FROZEN (R10: packing neutral; floor = dependent chain).
// Outputs: h (128,128,128) then x_skip (128,256,128), fp32, concatenated.

typedef __attribute__((ext_vector_type(8))) short bf16x8;
typedef __attribute__((ext_vector_type(4))) short bf16x4;
typedef __attribute__((ext_vector_type(4))) float f32x4;
using bf16 = __hip_bfloat16;

static __device__ __forceinline__ short f2s(float v) {
  union { bf16 b; short s; } u; u.b = (bf16)v; return u.s;
}
static __device__ __forceinline__ float s2f(short s) {
  union { short s; bf16 b; } u; u.s = s; return (float)u.b;
}

// packed stream index: (b, d, t) -> [b][g=d>>5][c=t>>3][dl=d&31][tt=t&7]
static __device__ __forceinline__ size_t pidx(int b, int d, int t) {
  return ((((size_t)b * 8 + (d >> 5)) * 32 + (t >> 3)) * 32 + (d & 31)) * 8 + (t & 7);
}

// ---------------------------------------------------------------------------
// prep_all: three independent prep jobs in one launch.
//  blocks [0,4096):    cvt_x -- x fp32 -> bf16 xb AND x_skip copy (out1)
//  blocks [4096,4416): prep_w -- ipw->bf16 ipwb; x_proj_w->wxb (rows 40+ = 0)
//  blocks [4416,4800): g_prep -- G_k[co,e] = sum_dm dwn[co,dm,k]*opw[dm,e]
// ---------------------------------------------------------------------------
__global__ __launch_bounds__(256) void prep_all(const float* __restrict__ x,
                                                const float* __restrict__ ipw,
                                                const float* __restrict__ xpw,
                                                const float* __restrict__ dwn,
                                                const float* __restrict__ opw,
                                                short* __restrict__ xb,
                                                float* __restrict__ out1,
                                                short* __restrict__ ipwb,
                                                short* __restrict__ wxb,
                                                short* __restrict__ G) {
  const int bid = blockIdx.x;
  if (bid < 4096) {
    int i = (bid * 256 + threadIdx.x) * 4;
    f32x4 v = *(const f32x4*)(x + i);
    bf16x4 o;
    o[0] = f2s(v[0]); o[1] = f2s(v[1]); o[2] = f2s(v[2]); o[3] = f2s(v[3]);
    *(bf16x4*)(xb + i) = o;
    *(f32x4*)(out1 + i) = v;
  } else if (bid < 4416) {
    int idx = (bid - 4096) * 256 + threadIdx.x;   // 0 .. 81919
    if (idx < 65536) {
      ipwb[idx] = f2s(ipw[idx]);
    } else {
      int j = idx - 65536;          // n*256 + k
      int n = j >> 8;
      wxb[j] = (n < 40) ? f2s(xpw[j]) : (short)0;
    }
  } else {
    const int jb = bid - 4416;      // 0 .. 383
    const int k  = jb >> 7;
    const int co = jb & 127;
    const int e  = threadIdx.x;
    float acc = 0.f;
    for (int dm = 0; dm < 128; ++dm) {
      acc += dwn[(co * 128 + dm) * 3 + k] * opw[dm * 256 + e];
    }
    G[(size_t)(k * 128 + co) * 256 + e] = f2s(acc);
  }
}

// ---------------------------------------------------------------------------
// front_k: fused in_proj + depthwise conv/silu + x_proj + delta.
// Block = (b, 64-t quarter), 512 blocks x 256 thr (4 waves), 75,264B LDS
// -> 2 blocks/CU, grid fully co-resident.
//  stage:  A-tile = xb rows t0-16..t0+63 (80x128 bf16), coalesced, 0-fill t<0.
//  xc GEMM: M=80 N=256 K=128; wave w owns n-cols w*64..; C-frags -> XC[t][d]
//           (rows 0..79 <-> t0-16..t0+63; rows 0..12 waste, harmless).
//  z GEMM:  M=64 N=256 K=128, nt-loop; wave w = m-tile w; silu C-frags ->
//           LT[64][72] transpose -> packed zP (inproj pattern).
//  conv:    thread (wave=16t, lane=d) x 4 dtiles from XC (+3-row halo);
//           results regs -> xcP packed; XC write-back after barrier.
//  x_proj:  wave w = m-tile w, N=64(40 used) K=256 from XC; dt->DTL,
//           B/C -> SBC fp32.
//  delta:   softplus(dt . dtw + dtb) -> dP packed.
// ---------------------------------------------------------------------------
__global__ __launch_bounds__(256, 2) void front_k(const short* __restrict__ xb,
                                                  const short* __restrict__ ipwb,
                                                  const short* __restrict__ wxb,
                                                  const float* __restrict__ cw,
                                                  const float* __restrict__ cb,
                                                  const float* __restrict__ dtw,
                                                  const float* __restrict__ dtb,
                                                  short* __restrict__ xcP,
                                                  short* __restrict__ dP,
                                                  short* __restrict__ zP,
                                                  float* __restrict__ SBC) {
  const int b  = blockIdx.x >> 2;
  const int t0 = (blockIdx.x & 3) * 64;
  const int w    = threadIdx.x >> 6;    // wave id (0..3)
  const int lane = threadIdx.x & 63;
  const int r16  = lane & 15;
  const int quad = lane >> 4;
  __shared__ short AL[80][136];         // A-tile [row=t-(t0-16)][k], pad 8
  __shared__ short XC[80][264];         // xc pre/post conv [row][d], pad 8
  __shared__ short LT[64][72];          // z transpose tile
  __shared__ float DTL[64][8];          // dt cols per t-local
  // ---- stage A-tile (coalesced b128, zero-fill t<0) ----
  for (int c = threadIdx.x; c < 1280; c += 256) {
    const int row = c >> 4;
    const int col = (c & 15) * 8;
    const int t = t0 - 16 + row;
    bf16x8 v = {};
    if (t >= 0) v = *(const bf16x8*)(xb + ((size_t)(b * 256 + t)) * 128 + col);
    *(bf16x8*)(&AL[row][col]) = v;
  }
  __syncthreads();
  // ---- xc GEMM: wave w -> cols w*64..w*64+63, M=80 ----
  {
    f32x4 acc[5][4] = {};
#pragma unroll
    for (int ks = 0; ks < 4; ++ks) {
      const int k0 = ks * 32;
      bf16x8 wf[4];
#pragma unroll
      for (int j = 0; j < 4; ++j)
        wf[j] = *(const bf16x8*)(ipwb +
                 (size_t)(w * 64 + j * 16 + r16) * 128 + quad * 8 + k0);
#pragma unroll
      for (int mt = 0; mt < 5; ++mt) {
        bf16x8 a = *(const bf16x8*)(&AL[mt * 16 + r16][quad * 8 + k0]);
#pragma unroll
        for (int j = 0; j < 4; ++j)
          acc[mt][j] = __builtin_amdgcn_mfma_f32_16x16x32_bf16(a, wf[j],
                                                               acc[mt][j], 0, 0, 0);
      }
    }
#pragma unroll
    for (int mt = 0; mt < 5; ++mt)
#pragma unroll
      for (int j = 0; j < 4; ++j)
#pragma unroll
        for (int r = 0; r < 4; ++r)
          XC[mt * 16 + quad * 4 + r][w * 64 + j * 16 + r16] = f2s(acc[mt][j][r]);
  }
  // ---- z GEMM + silu -> zP packed (LT transpose per nt) ----
  for (int nt = 0; nt < 4; ++nt) {
    f32x4 accz[4] = {};
#pragma unroll
    for (int ks = 0; ks < 4; ++ks) {
      const int k0 = ks * 32;
      bf16x8 a = *(const bf16x8*)(&AL[16 + w * 16 + r16][quad * 8 + k0]);
#pragma unroll
      for (int j = 0; j < 4; ++j) {
        bf16x8 wf = *(const bf16x8*)(ipwb +
                 (size_t)(256 + nt * 64 + j * 16 + r16) * 128 + quad * 8 + k0);
        accz[j] = __builtin_amdgcn_mfma_f32_16x16x32_bf16(a, wf, accz[j], 0, 0, 0);
      }
    }
    __syncthreads();                    // prior LT reads done (and XC epilogue)
#pragma unroll
    for (int j = 0; j < 4; ++j)
#pragma unroll
      for (int r = 0; r < 4; ++r) {
        float v = accz[j][r];
        LT[j * 16 + r16][w * 16 + quad * 4 + r] = f2s(v / (1.f + __expf(-v)));
      }
    __syncthreads();
#pragma unroll
    for (int it = 0; it < 2; ++it) {
      const int dw = (threadIdx.x >> 3) + it * 32;
      const int tc = (threadIdx.x & 7) * 8;
      bf16x8 v = *(const bf16x8*)(&LT[dw][tc]);
      *(bf16x8*)(zP + pidx(b, nt * 64 + dw, t0 + tc)) = v;
    }
  }
  __syncthreads();
  // ---- conv + silu: thread (wave=16t, lane=d) x 4 dtiles ----
  bf16x8 cv[4][2];
#pragma unroll
  for (int dt_ = 0; dt_ < 4; ++dt_) {
    const int d = dt_ * 64 + lane;
    const float w0 = cw[d * 4], w1 = cw[d * 4 + 1];
    const float w2 = cw[d * 4 + 2], w3 = cw[d * 4 + 3];
    const float bias = cb[d];
    const int rb_ = 16 + w * 16;        // XC row of first output t
    float p0 = s2f(XC[rb_ - 3][d]);
    float p1 = s2f(XC[rb_ - 2][d]);
    float p2 = s2f(XC[rb_ - 1][d]);
#pragma unroll
    for (int i = 0; i < 16; ++i) {
      const float cur = s2f(XC[rb_ + i][d]);
      const float a = bias + p0 * w0 + p1 * w1 + p2 * w2 + cur * w3;
      const short s = f2s(a / (1.f + __expf(-a)));
      cv[dt_][i >> 3][i & 7] = s;
      p0 = p1; p1 = p2; p2 = cur;
    }
    *(bf16x8*)(xcP + pidx(b, d, t0 + w * 16))     = cv[dt_][0];
    *(bf16x8*)(xcP + pidx(b, d, t0 + w * 16 + 8)) = cv[dt_][1];
  }
  __syncthreads();
#pragma unroll
  for (int dt_ = 0; dt_ < 4; ++dt_) {
    const int d = dt_ * 64 + lane;
#pragma unroll
    for (int i = 0; i < 16; ++i)
      XC[16 + w * 16 + i][d] = cv[dt_][i >> 3][i & 7];
  }
  __syncthreads();
  // ---- x_proj MFMA: wave w = m-tile w (16 t), N=64, K=256 ----
  {
    f32x4 ax[4] = {};
#pragma unroll
    for (int ks = 0; ks < 8; ++ks) {
      const int k0 = ks * 32;
      bf16x8 a = *(const bf16x8*)(&XC[16 + w * 16 + r16][quad * 8 + k0]);
#pragma unroll
      for (int j = 0; j < 4; ++j) {
        bf16x8 wf = *(const bf16x8*)(wxb + (size_t)(j * 16 + r16) * 256 + quad * 8 + k0);
        ax[j] = __builtin_amdgcn_mfma_f32_16x16x32_bf16(a, wf, ax[j], 0, 0, 0);
      }
    }
#pragma unroll
    for (int j = 0; j < 4; ++j) {
      const int col = j * 16 + r16;
#pragma unroll
      for (int r = 0; r < 4; ++r) {
        const int tl = w * 16 + quad * 4 + r;
        if (col < 8) {
          DTL[tl][col] = ax[j][r];
        } else if (col < 40) {
          SBC[((size_t)b * 256 + t0 + tl) * 32 + (col - 8)] = ax[j][r];
        }
      }
    }
  }
  __syncthreads();
  // ---- delta = softplus(dt . dtw + dtb) -> dP packed ----
#pragma unroll
  for (int dt_ = 0; dt_ < 4; ++dt_) {
    const int d = dt_ * 64 + lane;
    float wd[8];
#pragma unroll
    for (int j = 0; j < 8; ++j) wd[j] = dtw[d * 8 + j];
    const float bd = dtb[d];
    bf16x8 dv0, dv1;
#pragma unroll
    for (int i = 0; i < 16; ++i) {
      const int tl = w * 16 + i;
      const f32x4 p0 = *(const f32x4*)(&DTL[tl][0]);
      const f32x4 p1 = *(const f32x4*)(&DTL[tl][4]);
      float acc = bd;
#pragma unroll
      for (int j = 0; j < 4; ++j) acc += p0[j] * wd[j] + p1[j] * wd[4 + j];
      const float delta = (acc > 20.f) ? acc : __logf(1.f + __expf(acc));
      const short s = f2s(delta);
      if (i < 8) dv0[i] = s; else dv1[i - 8] = s;
    }
    *(bf16x8*)(dP + pidx(b, d, t0 + w * 16))     = dv0;
    *(bf16x8*)(dP + pidx(b, d, t0 + w * 16 + 8)) = dv1;
  }
}

// ---------------------------------------------------------------------------
// scan12 (FROZEN): R8 skeleton + packed u/d/z reads. Block = (b, group of 32
// d), 128 thr = 32 d x 4 lanes; lane owns 4 of 16 states, serial T=256.
// u/d/z packed streams: one contiguous 256B segment per wave-load. uu/dd/zz
// [4] named rotation, 4-phase unrolled; chunk c+4 issued right after chunk c
// consumed. S (B/C fp32) 2-phase LDS, 32KB. y scatter store (q==0).
// ---------------------------------------------------------------------------
#define LDS_S(SB, CH) do {                                                   \
    _Pragma("unroll")                                                        \
    for (int j_ = 0; j_ < 8; ++j_) {                                         \
      SBr[SB][j_] = *(const f32x4*)(&S[(CH) * 8 + j_][q * 4]);               \
      SCr[SB][j_] = *(const f32x4*)(&S[(CH) * 8 + j_][16 + q * 4]);          \
    }                                                                        \
  } while (0)

#define LDG(GB, CH) do {                                                     \
    if ((CH) < 32) {                                                         \
      uu[GB] = *(const bf16x8*)(xcP + pb + (size_t)(CH) * 256);              \
      dd[GB] = *(const bf16x8*)(dP + pb + (size_t)(CH) * 256);               \
      if (q == 0) zz[GB] = *(const bf16x8*)(zP + pb + (size_t)(CH) * 256);   \
    }                                                                        \
  } while (0)

#define CHUNK(GB, SB, CH) do {                                               \
    _Pragma("unroll")                                                        \
    for (int tt_ = 0; tt_ < 8; ++tt_) {                                      \
      const int t_ = (CH) * 8 + tt_;                                         \
      const float delta_ = s2f(dd[GB][tt_]);                                 \
      const float u_ = s2f(uu[GB][tt_]);                                     \
      const float du_ = delta_ * u_;                                         \
      const f32x4 Bq_ = SBr[SB][tt_];                                        \
      const f32x4 Cq_ = SCr[SB][tt_];                                        \
      float yt_ = 0.f;                                                       \
      _Pragma("unroll")                                                      \
      for (int n_ = 0; n_ < 4; ++n_) {                                       \
        const float dA_ = __builtin_amdgcn_exp2f(delta_ * A2[n_]);           \
        h[n_] = dA_ * h[n_] + du_ * Bq_[n_];                                 \
        yt_ += h[n_] * Cq_[n_];                                              \
      }                                                                      \
      yt_ += __shfl_xor(yt_, 1);                                             \
      yt_ += __shfl_xor(yt_, 2);                                             \
      if (q == 0)                                                            \
        yb[(rb + t_) * 256 + d] = f2s((yt_ + u_ * Dv) * s2f(zz[GB][tt_]));   \
    }                                                                        \
  } while (0)

__global__ __launch_bounds__(128, 2) void scan12(const float* __restrict__ SBC,
                                                 const short* __restrict__ xcP,
                                                 const short* __restrict__ dP,
                                                 const short* __restrict__ zP,
                                                 const float* __restrict__ alog,
                                                 const float* __restrict__ Dp,
                                                 short* __restrict__ yb) {
  const int g = blockIdx.x & 7;
  const int b = blockIdx.x >> 3;
  const int q = threadIdx.x & 3;
  const int dl = threadIdx.x >> 2;            // 0..31 within group
  const int d = g * 32 + dl;
  const size_t rb = (size_t)b * 256;
  __shared__ float S[256][32];                // B(16)|C(16) fp32 per t, 32 KB
  for (int i = threadIdx.x; i < 2048; i += 128) {
    *(f32x4*)(&S[i >> 3][(i & 7) * 4]) =
        *(const f32x4*)(SBC + (size_t)b * 8192 + i * 4);
  }
  float A2[4];
#pragma unroll
  for (int n = 0; n < 4; ++n)
    A2[n] = -__expf(alog[d * 16 + q * 4 + n]) * 1.44269504089f;
  const float Dv = Dp[d];
  float h[4] = {0.f, 0.f, 0.f, 0.f};
  // packed per-lane base: [b][g][c=0][dl][0]
  const size_t pb = (((size_t)b * 8 + g) * 32) * 256 + (size_t)dl * 8;
  f32x4 SBr[2][8], SCr[2][8];
  bf16x8 uu[4], dd[4];
  bf16x8 zz[4] = {};
  // 4-deep global prologue (issues before the LDS-fill barrier)
  LDG(0, 0); LDG(1, 1); LDG(2, 2); LDG(3, 3);
  __syncthreads();
  LDS_S(0, 0);
  for (int c = 0; c < 32; c += 4) {
    LDS_S(1, c + 1);
    CHUNK(0, 0, c);
    LDG(0, c + 4);
    LDS_S(0, c + 2);
    CHUNK(1, 1, c + 1);
    LDG(1, c + 5);
    LDS_S(1, c + 3);
    CHUNK(2, 0, c + 2);
    LDG(2, c + 6);
    if (c + 4 < 32) LDS_S(0, c + 4);
    CHUNK(3, 1, c + 3);
    LDG(3, c + 7);
  }
}

// ---------------------------------------------------------------------------
// od_k (R8 version, reverted): fused out_proj + strided down-conv + bias +
// LayerNorm.  pre[b,to,co] = sum_k yb[b,2to+k-1,:] . G_k[co,:] + db[co];
// out = LN(pre). Grid 256 x 256 thr (4 waves x 16 m-rows); K=768 via 3
// row-shifted K=256 segments; G L2-resident; LN via 16-lane shfl_xor.
// ---------------------------------------------------------------------------
__global__ __launch_bounds__(256) void od_k(const short* __restrict__ yb,
                                            const short* __restrict__ G,
                                            const float* __restrict__ db,
                                            const float* __restrict__ lng,
                                            const float* __restrict__ lnb,
                                            float* __restrict__ out) {
  const int wave = threadIdx.x >> 6;
  const int lane = threadIdx.x & 63;
  const int r16  = lane & 15;
  const int quad = lane >> 4;
  const int m_base = blockIdx.x * 64 + wave * 16;
  const int ma = m_base + r16;
  const int ba = ma >> 7, toa = ma & 127;
  f32x4 acc[8] = {};
  const bf16x8 az = {};
#pragma unroll
  for (int k = 0; k < 3; ++k) {
    const int tp = 2 * toa + k - 1;
    const bool valid = (tp >= 0) && (tp < 256);
    const int tpc = tp < 0 ? 0 : (tp > 255 ? 255 : tp);
    const short* Ap = yb + (size_t)(ba * 256 + tpc) * 256 + quad * 8;
    const short* Gp = G + (size_t)(k * 128 + r16) * 256 + quad * 8;
#pragma unroll
    for (int k0 = 0; k0 < 256; k0 += 32) {
      bf16x8 a = *(const bf16x8*)(Ap + k0);
      a = valid ? a : az;
#pragma unroll
      for (int j = 0; j < 8; ++j) {
        bf16x8 g = *(const bf16x8*)(Gp + (size_t)j * 16 * 256 + k0);
        acc[j] = __builtin_amdgcn_mfma_f32_16x16x32_bf16(a, g, acc[j], 0, 0, 0);
      }
    }
  }
  float dbv[8], g8[8], be8[8];
#pragma unroll
  for (int j = 0; j < 8; ++j) {
    const int col = j * 16 + r16;
    dbv[j] = db[col]; g8[j] = lng[col]; be8[j] = lnb[col];
  }
#pragma unroll
  for (int r = 0; r < 4; ++r) {
    float v[8];
    float s = 0.f;
#pragma unroll
    for (int j = 0; j < 8; ++j) { v[j] = acc[j][r] + dbv[j]; s += v[j]; }
    s += __shfl_xor(s, 1); s += __shfl_xor(s, 2);
    s += __shfl_xor(s, 4); s += __shfl_xor(s, 8);
    const float mu = s * (1.0f / 128.0f);
    float vs = 0.f;
#pragma unroll
    for (int j = 0; j < 8; ++j) { const float dd = v[j] - mu; vs += dd * dd; }
    vs += __shfl_xor(vs, 1); vs += __shfl_xor(vs, 2);
    vs += __shfl_xor(vs, 4); vs += __shfl_xor(vs, 8);
    const float rstd = rsqrtf(vs * (1.0f / 128.0f) + 1e-5f);
    const int rowm = m_base + quad * 4 + r;
#pragma unroll
    for (int j = 0; j < 8; ++j) {
      out[(size_t)rowm * 128 + j * 16 + r16] = (v[j] - mu) * rstd * g8[j] + be8[j];
    }
  }
}

// ---------------------------------------------------------------------------
// Workspace layout (bytes), peak 92,471,296 == proven-safe bound:
//   [0,16M)      yb bf16 (scan->od_k)
//   [16M,32M)    xcP bf16 packed (front_k->scan)
//   [32M,48M)    zP bf16 packed (front_k->scan)
//   [48M,64M)    dP bf16 packed (front_k->scan)
//   [64M,68.2M)  SBC fp32 4MB (front_k->scan)
//   [68.2M..71.5M) G bf16 196,608B (prep_all->od_k)
//   [72M,80.4M)  xb bf16 8.4MB (prep_all->front_k)
//   [88M,88.1M)  ipwb bf16 131,072B (prep_all->front_k)
// d_out staging: wxb (32KB bf16) at out0 base (od_k writes out0 LAST);
// out1 written once by prep_all.
// ---------------------------------------------------------------------------
static const size_t O_YB    = 0;
static const size_t O_XCP   = 16777216;
static const size_t O_ZP    = 33554432;
static const size_t O_DP    = 50331648;
static const size_t O_SBC   = 67108864;     // 4,194,304 B
static const size_t O_G     = 71303168;     // 196,608 B
static const size_t O_XB    = 75497472;
static const size_t O_IPWB  = 92274688;     // 131,072 B -> end 92,405,760

extern "C" void kernel_launch(void* const* d_in, const int* in_sizes, int n_in,
                              void* d_out, int out_size, void* d_ws, size_t ws_size,
                              hipStream_t stream) {
  const float* x    = (const float*)d_in[0];
  const float* ipw  = (const float*)d_in[1];
  const float* cw   = (const float*)d_in[2];
  const float* cb   = (const float*)d_in[3];
  const float* xpw  = (const float*)d_in[4];
  const float* dtw  = (const float*)d_in[5];
  const float* dtb  = (const float*)d_in[6];
  const float* alog = (const float*)d_in[7];
  const float* Dp   = (const float*)d_in[8];
  const float* opw  = (const float*)d_in[9];
  const float* dw   = (const float*)d_in[10];
  const float* db   = (const float*)d_in[11];
  const float* lng  = (const float*)d_in[12];
  const float* lnb  = (const float*)d_in[13];

  char*  ws     = (char*)d_ws;
  short* yb     = (short*)(ws + O_YB);
  short* xcP    = (short*)(ws + O_XCP);
  short* zP     = (short*)(ws + O_ZP);
  short* dP     = (short*)(ws + O_DP);
  float* SBC    = (float*)(ws + O_SBC);
  short* G      = (short*)(ws + O_G);
  short* xb     = (short*)(ws + O_XB);
  short* ipwb   = (short*)(ws + O_IPWB);
  float* out    = (float*)d_out;
  short* wxb    = (short*)out;             // out0 staging; od_k writes last
  float* out1   = out + 2097152;

  // 0. all prep: x->bf16 + x_skip copy; ipw/xpw->bf16; G = dwn @ opw
  prep_all<<<4800, 256, 0, stream>>>(x, ipw, xpw, dw, opw,
                                     xb, out1, ipwb, wxb, G);
  // 1. fused in_proj + conv/silu + x_proj + delta -> xcP/dP/zP/SBC
  front_k<<<512, 256, 0, stream>>>(xb, ipwb, wxb, cw, cb, dtw, dtb,
                                   xcP, dP, zP, SBC);
  // 2. state-parallel scan (FROZEN) -> yb
  scan12<<<1024, 128, 0, stream>>>(SBC, xcP, dP, zP, alog, Dp, yb);
  // 3. fused out_proj + down-conv + bias + LayerNorm -> output 0
  od_k<<<256, 256, 0, stream>>>(yb, G, db, lng, lnb, out);
}